// Round 1
// baseline (135.760 us; speedup 1.0000x reference)
//
#include <hip/hip_runtime.h>

#define NPTS 4096      // points per cloud
#define NB   4         // batch
#define KP   512       // keypoints
#define OTILE 512      // others staged per LDS tile
#define HUBER_C 0.01f

// ---------------- helpers ----------------

__device__ inline void wave_reduce_add_to(float v, float* target) {
    #pragma unroll
    for (int off = 32; off; off >>= 1) v += __shfl_down(v, off, 64);
    if ((threadIdx.x & 63) == 0) atomicAdd(target, v);
}

// ---------------- kernels ----------------

// ws layout: [0..15] float accumulators (only [0] used: nc_loss), [16..16+2*NB*NPTS) uint min bits
__global__ __launch_bounds__(256) void init_ws_kernel(unsigned* __restrict__ ws) {
    int i = blockIdx.x * 256 + threadIdx.x;   // grid covers exactly 2*NB*NPTS
    if (i < 16) ((float*)ws)[i] = 0.0f;
    ws[16 + i] = 0x7F800000u;                 // +inf
}

__global__ void zero_out_kernel(float* __restrict__ out) {
    if (threadIdx.x < 2) out[threadIdx.x] = 0.0f;
}

// Pairwise min squared distance. Layouts are (B,3,N) component-major.
// grid.x = q-chunks (N/256), grid.y = o-chunks, grid.z = dir*NB + b
// If minarr != null: atomicMin partial mins into ws. Else: full min per thread,
// apply huber, reduce, atomicAdd into gal_out.
__global__ __launch_bounds__(256) void pairwise_kernel(
    const float* __restrict__ srcT, const float* __restrict__ tgtT,
    unsigned* __restrict__ minarr, float* __restrict__ gal_out)
{
    __shared__ float ox[OTILE], oy[OTILE], oz[OTILE];
    const int tid = threadIdx.x;
    const int qc  = blockIdx.x;
    const int oc  = blockIdx.y;
    const int nOc = gridDim.y;
    const int dir = blockIdx.z >> 2;
    const int b   = blockIdx.z & 3;
    const float* qb = (dir ? tgtT : srcT) + b * 3 * NPTS;
    const float* ob = (dir ? srcT : tgtT) + b * 3 * NPTS;
    const int qi = qc * 256 + tid;
    const float qx = qb[qi], qy = qb[NPTS + qi], qz = qb[2 * NPTS + qi];
    const int chunk = NPTS / nOc;
    const int obeg  = oc * chunk;

    float m0 = 3.0e38f, m1 = 3.0e38f, m2 = 3.0e38f, m3 = 3.0e38f;
    for (int t0 = 0; t0 < chunk; t0 += OTILE) {
        __syncthreads();
        for (int t = tid; t < OTILE; t += 256) {
            int j = obeg + t0 + t;
            ox[t] = ob[j];
            oy[t] = ob[NPTS + j];
            oz[t] = ob[2 * NPTS + j];
        }
        __syncthreads();
        const float4* X4 = (const float4*)ox;
        const float4* Y4 = (const float4*)oy;
        const float4* Z4 = (const float4*)oz;
        #pragma unroll 4
        for (int g = 0; g < OTILE / 4; ++g) {
            float4 X = X4[g], Y = Y4[g], Z = Z4[g];
            float dx, dy, dz, d;
            dx = qx - X.x; dy = qy - Y.x; dz = qz - Z.x;
            d = fmaf(dx, dx, fmaf(dy, dy, dz * dz)); m0 = fminf(m0, d);
            dx = qx - X.y; dy = qy - Y.y; dz = qz - Z.y;
            d = fmaf(dx, dx, fmaf(dy, dy, dz * dz)); m1 = fminf(m1, d);
            dx = qx - X.z; dy = qy - Y.z; dz = qz - Z.z;
            d = fmaf(dx, dx, fmaf(dy, dy, dz * dz)); m2 = fminf(m2, d);
            dx = qx - X.w; dy = qy - Y.w; dz = qz - Z.w;
            d = fmaf(dx, dx, fmaf(dy, dy, dz * dz)); m3 = fminf(m3, d);
        }
    }
    float m = fminf(fminf(m0, m1), fminf(m2, m3));
    if (minarr) {
        // positive IEEE floats order-preserve as uints
        atomicMin(&minarr[(dir * NB + b) * NPTS + qi], __float_as_uint(m));
    } else {
        float h = (m < HUBER_C) ? 0.5f * m * m
                                : fmaf(HUBER_C, m, -0.5f * HUBER_C * HUBER_C);
        wave_reduce_add_to(h, gal_out);
    }
}

// keypoints: transformed = R @ src + t ; sum((transformed - tgt)^2)
__global__ __launch_bounds__(256) void kp_kernel(
    const float* __restrict__ skp, const float* __restrict__ tkp,
    const float* __restrict__ R, const float* __restrict__ T,
    float* __restrict__ acc)
{
    int i = blockIdx.x * 256 + threadIdx.x;   // 0..NB*KP-1
    int b = i >> 9;                           // KP = 512
    int n = i & (KP - 1);
    const float* r = R + b * 9;
    const float* t = T + b * 3;
    const float* s = skp + b * 3 * KP;
    const float* g = tkp + b * 3 * KP;
    float sx = s[n], sy = s[KP + n], sz = s[2 * KP + n];
    float sum = 0.f;
    #pragma unroll
    for (int d = 0; d < 3; ++d) {
        float v = fmaf(r[d*3+0], sx, fmaf(r[d*3+1], sy, fmaf(r[d*3+2], sz, t[d])))
                  - g[d * KP + n];
        sum = fmaf(v, v, sum);
    }
    wave_reduce_add_to(sum, acc);
}

// knn consensus: sum((a-b)^2) / k, vectorized float4 (count % 4 == 0)
__global__ __launch_bounds__(256) void knn_kernel(
    const float* __restrict__ a, const float* __restrict__ b,
    const int* __restrict__ kptr, float* __restrict__ acc)
{
    int i = blockIdx.x * 256 + threadIdx.x;
    float4 va = ((const float4*)a)[i];
    float4 vb = ((const float4*)b)[i];
    float dx = va.x - vb.x, dy = va.y - vb.y, dz = va.z - vb.z, dw = va.w - vb.w;
    float sum = fmaf(dx, dx, fmaf(dy, dy, fmaf(dz, dz, dw * dw)));
    float scale = 1.0f / (float)(*kptr);
    wave_reduce_add_to(sum * scale, acc);
}

__global__ __launch_bounds__(256) void finalize_kernel(
    const unsigned* __restrict__ minarr, const float* __restrict__ acc,
    float* __restrict__ out)
{
    __shared__ float red[4];
    int tid = threadIdx.x;
    float sum = 0.f;
    for (int i = tid; i < 2 * NB * NPTS; i += 256) {
        float x = __uint_as_float(minarr[i]);
        sum += (x < HUBER_C) ? 0.5f * x * x
                             : fmaf(HUBER_C, x, -0.5f * HUBER_C * HUBER_C);
    }
    #pragma unroll
    for (int off = 32; off; off >>= 1) sum += __shfl_down(sum, off, 64);
    if ((tid & 63) == 0) red[tid >> 6] = sum;
    __syncthreads();
    if (tid == 0) {
        out[1] = red[0] + red[1] + red[2] + red[3];  // gal
        out[0] = acc[0];                             // neighborhood consensus
    }
}

// ---------------- launch ----------------

extern "C" void kernel_launch(void* const* d_in, const int* in_sizes, int n_in,
                              void* d_out, int out_size, void* d_ws, size_t ws_size,
                              hipStream_t stream) {
    const float* skp  = (const float*)d_in[0];   // (B,3,KP)
    const float* tkp  = (const float*)d_in[1];   // (B,3,KP)
    const float* R    = (const float*)d_in[2];   // (B,3,3)
    const float* T    = (const float*)d_in[3];   // (B,3)
    const float* aknn = (const float*)d_in[4];   // (B,3,KP,K)
    const float* bknn = (const float*)d_in[5];   // (B,3,KP,K)
    const int*   kptr = (const int*)d_in[6];     // scalar k
    const float* srcT = (const float*)d_in[7];   // (B,3,N)
    const float* tgtT = (const float*)d_in[8];   // (B,3,N)
    float* out = (float*)d_out;

    const int knn_blocks = (in_sizes[4] / 4 + 255) / 256;   // 192 for 196608
    const int kp_blocks  = (NB * KP + 255) / 256;           // 8

    const size_t ws_need = (size_t)(16 + 2 * NB * NPTS) * sizeof(unsigned);
    if (ws_size >= ws_need) {
        unsigned* ws = (unsigned*)d_ws;
        float* acc = (float*)d_ws;          // ws float[0]
        unsigned* minarr = ws + 16;
        init_ws_kernel<<<(2 * NB * NPTS) / 256, 256, 0, stream>>>(ws);
        pairwise_kernel<<<dim3(NPTS / 256, 8, 2 * NB), 256, 0, stream>>>(
            srcT, tgtT, minarr, nullptr);
        kp_kernel<<<kp_blocks, 256, 0, stream>>>(skp, tkp, R, T, acc);
        knn_kernel<<<knn_blocks, 256, 0, stream>>>(aknn, bknn, kptr, acc);
        finalize_kernel<<<1, 256, 0, stream>>>(minarr, acc, out);
    } else {
        // fallback: no workspace — accumulate directly into zeroed d_out
        zero_out_kernel<<<1, 64, 0, stream>>>(out);
        pairwise_kernel<<<dim3(NPTS / 256, 1, 2 * NB), 256, 0, stream>>>(
            srcT, tgtT, nullptr, out + 1);
        kp_kernel<<<kp_blocks, 256, 0, stream>>>(skp, tkp, R, T, out);
        knn_kernel<<<knn_blocks, 256, 0, stream>>>(aknn, bknn, kptr, out);
    }
}

// Round 2
// 107.496 us; speedup vs baseline: 1.2629x; 1.2629x over previous
//
#include <hip/hip_runtime.h>

#define NPTS 4096      // points per cloud
#define NB   4         // batch
#define KP   512       // keypoints
#define HUBER_C 0.01f
#define HALF_PTS (NB * NPTS)          // 16384 (one cloud-set)
#define TOT_PTS  (2 * NB * NPTS)      // 32768

// ws layout: float4 pts4[TOT_PTS] (512 KB)  |  unsigned minarr[TOT_PTS] (128 KB)
// pts4[0..16383] = src points {x,y,z,|p|^2}, pts4[16384..32767] = tgt points.

// ---------------- helpers ----------------

__device__ inline void wave_reduce_add_to(float v, float* target) {
    #pragma unroll
    for (int off = 32; off; off >>= 1) v += __shfl_down(v, off, 64);
    if ((threadIdx.x & 63) == 0) atomicAdd(target, v);
}

__device__ inline float huber_f(float x) {
    return (x < HUBER_C) ? 0.5f * x * x
                         : fmaf(HUBER_C, x, -0.5f * HUBER_C * HUBER_C);
}

// ---------------- kernels ----------------

// grid = HALF_PTS/256 = 64 blocks. Builds pts4 for both clouds, inits minarr, zeroes out.
__global__ __launch_bounds__(256) void prep_kernel(
    const float* __restrict__ srcT, const float* __restrict__ tgtT,
    float4* __restrict__ pts4, unsigned* __restrict__ minarr,
    float* __restrict__ out)
{
    int i = blockIdx.x * 256 + threadIdx.x;    // [0, HALF_PTS)
    int b = i >> 12, j = i & (NPTS - 1);
    const float* s = srcT + b * 3 * NPTS;
    const float* t = tgtT + b * 3 * NPTS;
    float sx = s[j], sy = s[NPTS + j], sz = s[2 * NPTS + j];
    float tx = t[j], ty = t[NPTS + j], tz = t[2 * NPTS + j];
    pts4[i]            = make_float4(sx, sy, sz, fmaf(sx, sx, fmaf(sy, sy, sz * sz)));
    pts4[HALF_PTS + i] = make_float4(tx, ty, tz, fmaf(tx, tx, fmaf(ty, ty, tz * tz)));
    minarr[i] = 0x7F800000u;
    minarr[HALF_PTS + i] = 0x7F800000u;
    if (i < 2) out[i] = 0.0f;
}

// Fused main: blocks [0,512) = gal pairwise-min; then knn blocks; then kp blocks.
__global__ __launch_bounds__(256) void main_kernel(
    const float4* __restrict__ pts4, unsigned* __restrict__ minarr,
    const float* __restrict__ skp, const float* __restrict__ tkp,
    const float* __restrict__ R, const float* __restrict__ T,
    const float* __restrict__ aknn, const float* __restrict__ bknn,
    const int* __restrict__ kptr, float* __restrict__ out,
    int knn_blocks, int knn_quads)
{
    const int bid = blockIdx.x;
    const int tid = threadIdx.x;

    if (bid < 512) {
        // ---- global-align pairwise min ----
        // dir0: queries = src (loss_1, per-pred min over gts); dir1: queries = tgt.
        const int dir = bid & 1;
        const int b   = (bid >> 1) & 3;
        const int oc  = (bid >> 3) & 7;      // 8 other-stripes of 512
        const int qc  = bid >> 6;            // 8 query-chunks of 512
        const float4* q4 = pts4 + (dir ? HALF_PTS : 0) + b * NPTS;
        const float4* o4 = pts4 + (dir ? 0 : HALF_PTS) + b * NPTS + oc * 512;
        const int qi0 = qc * 512 + tid;
        const int qi1 = qi0 + 256;
        const float4 qa = q4[qi0];
        const float4 qb = q4[qi1];
        const float ax = -2.0f * qa.x, ay = -2.0f * qa.y, az = -2.0f * qa.z;
        const float bx = -2.0f * qb.x, by = -2.0f * qb.y, bz = -2.0f * qb.z;
        float ma = 3.0e38f, mb = 3.0e38f;
        #pragma unroll 4
        for (int j = 0; j < 512; j += 2) {
            // block-uniform index -> scalar/uniform load, no LDS
            float4 o0 = o4[j], o1 = o4[j + 1];
            float ta0 = fmaf(o0.x, ax, fmaf(o0.y, ay, fmaf(o0.z, az, o0.w)));
            float ta1 = fmaf(o1.x, ax, fmaf(o1.y, ay, fmaf(o1.z, az, o1.w)));
            ma = fminf(ma, fminf(ta0, ta1));                 // -> v_min3_f32
            float tb0 = fmaf(o0.x, bx, fmaf(o0.y, by, fmaf(o0.z, bz, o0.w)));
            float tb1 = fmaf(o1.x, bx, fmaf(o1.y, by, fmaf(o1.z, bz, o1.w)));
            mb = fminf(mb, fminf(tb0, tb1));
        }
        const float da = qa.w + ma;          // >= 0: uint atomicMin order-safe
        const float db = qb.w + mb;
        unsigned* marr = minarr + (dir * NB + b) * NPTS;
        atomicMin(&marr[qi0], __float_as_uint(da));
        atomicMin(&marr[qi1], __float_as_uint(db));
    } else if (bid < 512 + knn_blocks) {
        // ---- knn consensus: sum((a-b)^2)/k ----
        int i = (bid - 512) * 256 + tid;
        float sum = 0.0f;
        if (i < knn_quads) {
            float4 va = ((const float4*)aknn)[i];
            float4 vb = ((const float4*)bknn)[i];
            float dx = va.x - vb.x, dy = va.y - vb.y;
            float dz = va.z - vb.z, dw = va.w - vb.w;
            sum = fmaf(dx, dx, fmaf(dy, dy, fmaf(dz, dz, dw * dw)));
        }
        float scale = 1.0f / (float)(*kptr);
        wave_reduce_add_to(sum * scale, out);
    } else {
        // ---- keypoints: sum((R@s + t - g)^2) ----
        int i = (bid - 512 - knn_blocks) * 256 + tid;   // [0, NB*KP)
        int b = i >> 9;
        int n = i & (KP - 1);
        const float* r = R + b * 9;
        const float* t = T + b * 3;
        const float* s = skp + b * 3 * KP;
        const float* g = tkp + b * 3 * KP;
        float sx = s[n], sy = s[KP + n], sz = s[2 * KP + n];
        float sum = 0.0f;
        #pragma unroll
        for (int d = 0; d < 3; ++d) {
            float v = fmaf(r[d*3+0], sx, fmaf(r[d*3+1], sy, fmaf(r[d*3+2], sz, t[d])))
                      - g[d * KP + n];
            sum = fmaf(v, v, sum);
        }
        wave_reduce_add_to(sum, out);
    }
}

// grid = 32 blocks; huber over the 32768 mins -> out[1]
__global__ __launch_bounds__(256) void finalize_kernel(
    const unsigned* __restrict__ minarr, float* __restrict__ out)
{
    int base = blockIdx.x * 1024 + threadIdx.x;
    float sum = 0.0f;
    #pragma unroll
    for (int r = 0; r < 4; ++r)
        sum += huber_f(__uint_as_float(minarr[base + r * 256]));
    wave_reduce_add_to(sum, out + 1);
}

// ---------------- fallback (no workspace) ----------------

__global__ void zero_out_kernel(float* __restrict__ out) {
    if (threadIdx.x < 2) out[threadIdx.x] = 0.0f;
}

__global__ __launch_bounds__(256) void gal_direct_kernel(
    const float* __restrict__ srcT, const float* __restrict__ tgtT,
    float* __restrict__ gal_out)
{
    const int dir = blockIdx.y >> 2;
    const int b   = blockIdx.y & 3;
    const float* qb = (dir ? tgtT : srcT) + b * 3 * NPTS;
    const float* ob = (dir ? srcT : tgtT) + b * 3 * NPTS;
    const int qi = blockIdx.x * 256 + threadIdx.x;
    const float qx = qb[qi], qy = qb[NPTS + qi], qz = qb[2 * NPTS + qi];
    float m = 3.0e38f;
    #pragma unroll 4
    for (int j = 0; j < NPTS; ++j) {
        float dx = qx - ob[j], dy = qy - ob[NPTS + j], dz = qz - ob[2 * NPTS + j];
        m = fminf(m, fmaf(dx, dx, fmaf(dy, dy, dz * dz)));
    }
    wave_reduce_add_to(huber_f(m), gal_out);
}

__global__ __launch_bounds__(256) void kp_kernel(
    const float* __restrict__ skp, const float* __restrict__ tkp,
    const float* __restrict__ R, const float* __restrict__ T,
    float* __restrict__ acc)
{
    int i = blockIdx.x * 256 + threadIdx.x;
    int b = i >> 9, n = i & (KP - 1);
    const float* r = R + b * 9;
    const float* t = T + b * 3;
    const float* s = skp + b * 3 * KP;
    const float* g = tkp + b * 3 * KP;
    float sx = s[n], sy = s[KP + n], sz = s[2 * KP + n];
    float sum = 0.0f;
    #pragma unroll
    for (int d = 0; d < 3; ++d) {
        float v = fmaf(r[d*3+0], sx, fmaf(r[d*3+1], sy, fmaf(r[d*3+2], sz, t[d])))
                  - g[d * KP + n];
        sum = fmaf(v, v, sum);
    }
    wave_reduce_add_to(sum, acc);
}

__global__ __launch_bounds__(256) void knn_kernel(
    const float* __restrict__ a, const float* __restrict__ b,
    const int* __restrict__ kptr, float* __restrict__ acc, int quads)
{
    int i = blockIdx.x * 256 + threadIdx.x;
    float sum = 0.0f;
    if (i < quads) {
        float4 va = ((const float4*)a)[i];
        float4 vb = ((const float4*)b)[i];
        float dx = va.x - vb.x, dy = va.y - vb.y;
        float dz = va.z - vb.z, dw = va.w - vb.w;
        sum = fmaf(dx, dx, fmaf(dy, dy, fmaf(dz, dz, dw * dw)));
    }
    float scale = 1.0f / (float)(*kptr);
    wave_reduce_add_to(sum * scale, acc);
}

// ---------------- launch ----------------

extern "C" void kernel_launch(void* const* d_in, const int* in_sizes, int n_in,
                              void* d_out, int out_size, void* d_ws, size_t ws_size,
                              hipStream_t stream) {
    const float* skp  = (const float*)d_in[0];   // (B,3,KP)
    const float* tkp  = (const float*)d_in[1];   // (B,3,KP)
    const float* R    = (const float*)d_in[2];   // (B,3,3)
    const float* T    = (const float*)d_in[3];   // (B,3)
    const float* aknn = (const float*)d_in[4];   // (B,3,KP,K)
    const float* bknn = (const float*)d_in[5];   // (B,3,KP,K)
    const int*   kptr = (const int*)d_in[6];     // scalar k
    const float* srcT = (const float*)d_in[7];   // (B,3,N)
    const float* tgtT = (const float*)d_in[8];   // (B,3,N)
    float* out = (float*)d_out;

    const int knn_quads  = in_sizes[4] / 4;                 // 49152
    const int knn_blocks = (knn_quads + 255) / 256;         // 192
    const int kp_blocks  = (NB * KP + 255) / 256;           // 8

    const size_t ws_need = (size_t)TOT_PTS * 16 + (size_t)TOT_PTS * 4;
    if (ws_size >= ws_need) {
        float4*   pts4   = (float4*)d_ws;
        unsigned* minarr = (unsigned*)((char*)d_ws + (size_t)TOT_PTS * 16);
        prep_kernel<<<HALF_PTS / 256, 256, 0, stream>>>(srcT, tgtT, pts4, minarr, out);
        main_kernel<<<512 + knn_blocks + kp_blocks, 256, 0, stream>>>(
            pts4, minarr, skp, tkp, R, T, aknn, bknn, kptr, out,
            knn_blocks, knn_quads);
        finalize_kernel<<<32, 256, 0, stream>>>(minarr, out);
    } else {
        zero_out_kernel<<<1, 64, 0, stream>>>(out);
        gal_direct_kernel<<<dim3(NPTS / 256, 2 * NB), 256, 0, stream>>>(srcT, tgtT, out + 1);
        kp_kernel<<<kp_blocks, 256, 0, stream>>>(skp, tkp, R, T, out);
        knn_kernel<<<knn_blocks, 256, 0, stream>>>(aknn, bknn, kptr, out, knn_quads);
    }
}